// Round 1
// baseline (825.259 us; speedup 1.0000x reference)
//
#include <hip/hip_runtime.h>
#include <math.h>

#define B 256
#define F 512
#define C 100000
#define S_SCALE 64.0f
#define M_MARGIN 0.4f
#define K_VP 0.7f

#define BN 32
#define NTILES (C / BN)   // 3125 exact: C % 32 == 0, no tail guards needed

typedef __bf16 bf16x8 __attribute__((ext_vector_type(8)));
typedef float  floatx4 __attribute__((ext_vector_type(4)));

// ---------- fused: emb = l2norm(input) -> swizzled bf16 A + newrows (exact fp32) ----------
// embb_sw layout: A-frag for (rowtile R, kstep ks) at 1KB region ((R*16+ks)*64 + lane)*16B,
// lane = (row&15) + 16*q, element j: k = ks*32 + q*8 + j.
__global__ void embnew_kernel(const float* __restrict__ input, const float* __restrict__ queue,
                              const int* __restrict__ label,
                              __bf16* __restrict__ embb_sw, float* __restrict__ newrows) {
    int i = blockIdx.x;
    int t = threadIdx.x;
    const float* x = input + (size_t)i * F;
    float x0 = x[t], x1 = x[t + 256];
    float p = x0 * x0 + x1 * x1;
    __shared__ float red[4];
    for (int off = 32; off > 0; off >>= 1) p += __shfl_down(p, off, 64);
    if ((t & 63) == 0) red[t >> 6] = p;
    __syncthreads();
    float tot = red[0] + red[1] + red[2] + red[3];
    float inv = 1.0f / fmaxf(sqrtf(tot), 1e-5f);
    float e0 = x0 * inv, e1 = x1 * inv;
    // swizzled bf16 writes for k=t and k=t+256
    {
        int R = i >> 4, ln = i & 15;
        int k = t;
        embb_sw[(size_t)(((R * 16 + (k >> 5)) * 64 + ln + 16 * ((k & 31) >> 3)) * 8 + (k & 7))] = (__bf16)e0;
        k = t + 256;
        embb_sw[(size_t)(((R * 16 + (k >> 5)) * 64 + ln + 16 * ((k & 31) >> 3)) * 8 + (k & 7))] = (__bf16)e1;
    }
    // newrows (needs only this row's emb)
    int l = label[i];
    const float* qr = queue + (size_t)l * F;
    float q0 = qr[t], q1 = qr[t + 256];
    float pd = q0 * e0 + q1 * e1;
    __syncthreads();
    for (int off = 32; off > 0; off >>= 1) pd += __shfl_down(pd, off, 64);
    if ((t & 63) == 0) red[t >> 6] = pd;
    __syncthreads();
    float drift = red[0] + red[1] + red[2] + red[3];
    float f = drift / (1.0f + fabsf(drift));   // softsign
    float v0 = f * q0 + (1.0f - f) * e0;
    float v1 = f * q1 + (1.0f - f) * e1;
    float p2 = v0 * v0 + v1 * v1;
    __syncthreads();
    for (int off = 32; off > 0; off >>= 1) p2 += __shfl_down(p2, off, 64);
    if ((t & 63) == 0) red[t >> 6] = p2;
    __syncthreads();
    float tot2 = red[0] + red[1] + red[2] + red[3];
    float inv2 = 1.0f / fmaxf(sqrtf(tot2), 1e-12f);
    newrows[(size_t)i * F + t]       = v0 * inv2;
    newrows[(size_t)i * F + t + 256] = v1 * inv2;
}

// ---------- map[c] = -1 ; negacc = 0 ----------
__global__ void init_kernel(int* __restrict__ map, float* __restrict__ negacc) {
    int idx = blockIdx.x * 256 + threadIdx.x;
    if (idx < C) map[idx] = -1;
    if (idx < 2 * B) negacc[idx] = 0.0f;
}

// ---------- last-occurrence-wins scatter (numpy queue[label]=rows semantics) ----------
__global__ void scatter_kernel(const int* __restrict__ label, int* __restrict__ map) {
    atomicMax(&map[label[threadIdx.x]], (int)threadIdx.x);
}

// ---------- bf16 MFMA GEMM, BN=32 tile, fragment-region LDS (conflict-free), 4 blocks/CU ----
// LDS B layout: 32 regions of 1KB, region r = ks*2 + ct holds the B-fragment for that
// (ks, 16-col group): lane = (c&15) + 16*q at offset lane*16B, elements k = ks*32 + q*8 + j.
// Staging: thread (cl=(tid>>2)&31, s=tid&3, h=tid>>7) owns col c0+cl, slots ks=h*8+j2, q=s.
// Each wave's 64 ds_write_b128 exactly tile one region -> zero bank conflicts.
// Column sumsq is accumulated in registers during staging (each thread touches one column only).
__global__ __launch_bounds__(256, 4) void gemm_epl_kernel(
        const __bf16* __restrict__ embb_sw,
        const float* __restrict__ weight,
        const float* __restrict__ queue,
        const float* __restrict__ newrows,
        const int* __restrict__ map,
        const int* __restrict__ label,
        float* __restrict__ negacc,
        float* __restrict__ posvals) {
    int bx = blockIdx.x;
    int src = bx / NTILES;
    int tile = bx - src * NTILES;
    int c0 = tile * BN;
    int tid = threadIdx.x;
    int w = tid >> 6;
    int l = tid & 63;
    int ln = l & 15;
    int q = l >> 4;

    __shared__ __align__(16) __bf16 bS[32 * 512];   // 32 KB, frag-region layout
    __shared__ float colpart_s[BN][9];              // +1 pad word to break reduce stride
    __shared__ float colinv_s[BN];
    __shared__ int label_s[B];

    label_s[tid] = label[tid];

    // ---- staging + register sumsq: 16 dwordx4 loads, 8 conflict-free b128 LDS writes
    {
        int cl = (tid >> 2) & 31;   // column within tile
        int s  = tid & 3;           // q-slot
        int h  = tid >> 7;          // ks half: 0 -> ks 0..7, 1 -> ks 8..15
        int c  = c0 + cl;           // always < C (no tail)
        const float* bp;
        if (src == 0) bp = weight + (size_t)c * F;
        else {
            int mi = map[c];
            bp = (mi >= 0) ? newrows + (size_t)mi * F : queue + (size_t)c * F;
        }
        int ct = cl >> 4, lnc = cl & 15;
        float ss = 0.f;
#pragma unroll
        for (int j2 = 0; j2 < 8; ++j2) {
            int ks = h * 8 + j2;
            int kf = (s + 4 * ks) * 8;              // float offset in column; 32B contiguous/lane
            float4 u0 = *(const float4*)(bp + kf);
            float4 u1 = *(const float4*)(bp + kf + 4);
            ss += u0.x * u0.x + u0.y * u0.y + u0.z * u0.z + u0.w * u0.w
                + u1.x * u1.x + u1.y * u1.y + u1.z * u1.z + u1.w * u1.w;
            bf16x8 bv;
            bv[0] = (__bf16)u0.x; bv[1] = (__bf16)u0.y; bv[2] = (__bf16)u0.z; bv[3] = (__bf16)u0.w;
            bv[4] = (__bf16)u1.x; bv[5] = (__bf16)u1.y; bv[6] = (__bf16)u1.z; bv[7] = (__bf16)u1.w;
            *(bf16x8*)&bS[(size_t)(((ks * 2 + ct) * 64 + lnc + 16 * s) * 8)] = bv;
        }
        colpart_s[cl][h * 4 + s] = ss;
    }
    __syncthreads();

    if (tid < BN) {
        float ssum = 0.f;
#pragma unroll
        for (int p = 0; p < 8; ++p) ssum += colpart_s[tid][p];
        float eps = (src == 0) ? 1e-5f : 1e-12f;
        colinv_s[tid] = 1.0f / fmaxf(sqrtf(ssum), eps);
    }

    // ---- MFMA main loop: wave w -> rows 64w..64w+63; A-frags stream from L2 (1KB coalesced);
    //      B-frags: conflict-free lane-linear ds_read_b128 from frag regions.
    floatx4 acc[4][2];
#pragma unroll
    for (int rt = 0; rt < 4; ++rt)
#pragma unroll
        for (int ct = 0; ct < 2; ++ct) acc[rt][ct] = (floatx4){0.f, 0.f, 0.f, 0.f};

#pragma unroll
    for (int ks = 0; ks < 16; ++ks) {
        bf16x8 af[4], bfr[2];
#pragma unroll
        for (int rt = 0; rt < 4; ++rt)
            af[rt] = *(const bf16x8*)(embb_sw + ((size_t)(((w * 4 + rt) * 16 + ks) * 64 + l) << 3));
#pragma unroll
        for (int ct = 0; ct < 2; ++ct)
            bfr[ct] = *(const bf16x8*)&bS[(size_t)(((ks * 2 + ct) * 64 + l) * 8)];
#pragma unroll
        for (int rt = 0; rt < 4; ++rt)
#pragma unroll
            for (int ct = 0; ct < 2; ++ct)
                acc[rt][ct] = __builtin_amdgcn_mfma_f32_16x16x32_bf16(af[rt], bfr[ct], acc[rt][ct], 0, 0, 0);
    }

    __syncthreads();   // colinv_s (written by tid<32 after first barrier) now visible to all

    // ---- epilogue: cos = acc * colinv; label col -> posvals; others -> sum exp(64*cos)
#pragma unroll
    for (int rt = 0; rt < 4; ++rt) {
#pragma unroll
        for (int r = 0; r < 4; ++r) {
            int row = w * 64 + rt * 16 + q * 4 + r;
            int lab = label_s[row];
            float sum = 0.f;
#pragma unroll
            for (int ct = 0; ct < 2; ++ct) {
                int c = c0 + ct * 16 + ln;
                float cosv = acc[rt][ct][r] * colinv_s[ct * 16 + ln];
                if (c == lab) posvals[src * B + row] = cosv;  // unique writer per (src,row)
                else sum += __expf(S_SCALE * cosv);
            }
            sum += __shfl_xor(sum, 1, 64);
            sum += __shfl_xor(sum, 2, 64);
            sum += __shfl_xor(sum, 4, 64);
            sum += __shfl_xor(sum, 8, 64);
            if (ln == 0) atomicAdd(&negacc[src * B + row], sum);
        }
    }
}

// ---------- final EPL loss ----------
__global__ void loss_kernel(const float* __restrict__ negacc, const float* __restrict__ posvals,
                            float* __restrict__ out) {
    int t = threadIdx.x;  // 256
    float l1 = log1pf(negacc[t] * __expf(-S_SCALE * (posvals[t] - M_MARGIN)));
    float l2 = log1pf(negacc[B + t] * __expf(-S_SCALE * (1.0f - K_VP) * posvals[B + t]));
    float p = l1 + l2;
    __shared__ float red[4];
    for (int off = 32; off > 0; off >>= 1) p += __shfl_down(p, off, 64);
    if ((t & 63) == 0) red[t >> 6] = p;
    __syncthreads();
    if (t == 0) out[0] = (red[0] + red[1] + red[2] + red[3]) / (2.0f * B);
}

extern "C" void kernel_launch(void* const* d_in, const int* in_sizes, int n_in,
                              void* d_out, int out_size, void* d_ws, size_t ws_size,
                              hipStream_t stream) {
    const float* input  = (const float*)d_in[0];
    const float* weight = (const float*)d_in[1];
    const float* queue  = (const float*)d_in[2];
    const int*   label  = (const int*)d_in[3];
    float* out = (float*)d_out;

    char* ws = (char*)d_ws;
    __bf16* embb_sw = (__bf16*)(ws);                         // 256 KB
    float*  newrows = (float*)(ws + (256 << 10));            // 512 KB
    float*  negacc  = (float*)(ws + (768 << 10));            // 2 KB
    float*  posvals = (float*)(ws + (768 << 10) + 2048);     // 2 KB
    int*    map     = (int*)  (ws + (768 << 10) + 4096);     // 400 KB

    init_kernel<<<(C + 255) / 256, 256, 0, stream>>>(map, negacc);
    scatter_kernel<<<1, B, 0, stream>>>(label, map);
    embnew_kernel<<<B, 256, 0, stream>>>(input, queue, label, embb_sw, newrows);
    gemm_epl_kernel<<<2 * NTILES, 256, 0, stream>>>(embb_sw, weight, queue, newrows, map,
                                                    label, negacc, posvals);
    loss_kernel<<<1, 256, 0, stream>>>(negacc, posvals, out);
}

// Round 2
// 478.757 us; speedup vs baseline: 1.7238x; 1.7238x over previous
//
#include <hip/hip_runtime.h>
#include <math.h>

#define B 256
#define F 512
#define C 100000
#define S_SCALE 64.0f
#define M_MARGIN 0.4f
#define K_VP 0.7f

#define BN 64
#define NTILES ((C + BN - 1) / BN)   // 1563 (last tile has 32 valid cols)

typedef __bf16 bf16x8 __attribute__((ext_vector_type(8)));
typedef float  floatx4 __attribute__((ext_vector_type(4)));

// ---------- fused: emb = l2norm(input) -> swizzled bf16 A + newrows (exact fp32) ----------
// embb_sw layout: A-frag for (rowtile R, kstep ks) at 1KB region ((R*16+ks)*64 + lane)*16B,
// lane = (row&15) + 16*q, element j: k = ks*32 + q*8 + j.
__global__ void embnew_kernel(const float* __restrict__ input, const float* __restrict__ queue,
                              const int* __restrict__ label,
                              __bf16* __restrict__ embb_sw, float* __restrict__ newrows) {
    int i = blockIdx.x;
    int t = threadIdx.x;
    const float* x = input + (size_t)i * F;
    float x0 = x[t], x1 = x[t + 256];
    float p = x0 * x0 + x1 * x1;
    __shared__ float red[4];
    for (int off = 32; off > 0; off >>= 1) p += __shfl_down(p, off, 64);
    if ((t & 63) == 0) red[t >> 6] = p;
    __syncthreads();
    float tot = red[0] + red[1] + red[2] + red[3];
    float inv = 1.0f / fmaxf(sqrtf(tot), 1e-5f);
    float e0 = x0 * inv, e1 = x1 * inv;
    // swizzled bf16 writes for k=t and k=t+256
    {
        int R = i >> 4, ln = i & 15;
        int k = t;
        embb_sw[(size_t)(((R * 16 + (k >> 5)) * 64 + ln + 16 * ((k & 31) >> 3)) * 8 + (k & 7))] = (__bf16)e0;
        k = t + 256;
        embb_sw[(size_t)(((R * 16 + (k >> 5)) * 64 + ln + 16 * ((k & 31) >> 3)) * 8 + (k & 7))] = (__bf16)e1;
    }
    // newrows (needs only this row's emb)
    int l = label[i];
    const float* qr = queue + (size_t)l * F;
    float q0 = qr[t], q1 = qr[t + 256];
    float pd = q0 * e0 + q1 * e1;
    __syncthreads();
    for (int off = 32; off > 0; off >>= 1) pd += __shfl_down(pd, off, 64);
    if ((t & 63) == 0) red[t >> 6] = pd;
    __syncthreads();
    float drift = red[0] + red[1] + red[2] + red[3];
    float f = drift / (1.0f + fabsf(drift));   // softsign
    float v0 = f * q0 + (1.0f - f) * e0;
    float v1 = f * q1 + (1.0f - f) * e1;
    float p2 = v0 * v0 + v1 * v1;
    __syncthreads();
    for (int off = 32; off > 0; off >>= 1) p2 += __shfl_down(p2, off, 64);
    if ((t & 63) == 0) red[t >> 6] = p2;
    __syncthreads();
    float tot2 = red[0] + red[1] + red[2] + red[3];
    float inv2 = 1.0f / fmaxf(sqrtf(tot2), 1e-12f);
    newrows[(size_t)i * F + t]       = v0 * inv2;
    newrows[(size_t)i * F + t + 256] = v1 * inv2;
}

// ---------- map[c] = -1 ----------
__global__ void init_kernel(int* __restrict__ map) {
    int idx = blockIdx.x * 256 + threadIdx.x;
    if (idx < C) map[idx] = -1;
}

// ---------- last-occurrence-wins scatter (numpy queue[label]=rows semantics) ----------
__global__ void scatter_kernel(const int* __restrict__ label, int* __restrict__ map) {
    atomicMax(&map[label[threadIdx.x]], (int)threadIdx.x);
}

// ---------- bf16 MFMA GEMM, BN=64, 8 waves, frag-region LDS, NO ATOMICS ----------
// LDS B layout: 64 regions of 1KB; region (ks*4+ct) holds the B-fragment for that
// (ks, 16-col group): slot = lane = (c&15)+16*q at offset lane*16B, elems k = ks*32+q*8+j.
// Staging: wave w -> ct=w&3, h=w>>2; lane l -> col c0+ct*16+(l&15), q-slot l>>4,
// ks = h*8+j2. slot==lane -> every ds_write_b128 is lane-linear (conflict-free).
// Column sumsq accumulates in registers during staging (each thread owns one column).
// Per-row negative-exp partial sums go to partials[] via PLAIN stores (one per row per
// block, unique address) -- replaces 0.8M contended device atomics (16B/atomic
// memory-side writes were the round-1 bottleneck: WRITE_SIZE == 16B * n_atomics).
__global__ __launch_bounds__(512, 4) void gemm_epl_kernel(
        const __bf16* __restrict__ embb_sw,
        const float* __restrict__ weight,
        const float* __restrict__ queue,
        const float* __restrict__ newrows,
        const int* __restrict__ map,
        const int* __restrict__ label,
        float* __restrict__ partials,
        float* __restrict__ posvals) {
    int bx = blockIdx.x;
    int src = bx / NTILES;
    int tile = bx - src * NTILES;
    int c0 = tile * BN;
    int tid = threadIdx.x;
    int w = tid >> 6;          // 0..7
    int l = tid & 63;
    int ln = l & 15;
    int q = l >> 4;

    __shared__ __align__(16) __bf16 bS[64 * 512];   // 64 KB, frag-region layout
    __shared__ float colpart_s[BN][9];              // padded
    __shared__ float colinv_s[BN];
    __shared__ int label_s[B];

    if (tid < B) label_s[tid] = label[tid];

    // ---- staging + register sumsq: 16 dwordx4 loads, 8 lane-linear b128 LDS writes
    {
        int ct = w & 3, h = w >> 2;
        int cl = ct * 16 + ln;
        int c = c0 + cl;
        const float* bp = nullptr;
        if (c < C) {
            if (src == 0) bp = weight + (size_t)c * F;
            else {
                int mi = map[c];
                bp = (mi >= 0) ? newrows + (size_t)mi * F : queue + (size_t)c * F;
            }
        }
        float ss = 0.f;
#pragma unroll
        for (int j2 = 0; j2 < 8; ++j2) {
            int ks = h * 8 + j2;
            int kf = (q + 4 * ks) * 8;              // 32B contiguous per lane
            float4 u0 = make_float4(0.f, 0.f, 0.f, 0.f);
            float4 u1 = make_float4(0.f, 0.f, 0.f, 0.f);
            if (bp) {
                u0 = *(const float4*)(bp + kf);
                u1 = *(const float4*)(bp + kf + 4);
            }
            ss += u0.x * u0.x + u0.y * u0.y + u0.z * u0.z + u0.w * u0.w
                + u1.x * u1.x + u1.y * u1.y + u1.z * u1.z + u1.w * u1.w;
            bf16x8 bv;
            bv[0] = (__bf16)u0.x; bv[1] = (__bf16)u0.y; bv[2] = (__bf16)u0.z; bv[3] = (__bf16)u0.w;
            bv[4] = (__bf16)u1.x; bv[5] = (__bf16)u1.y; bv[6] = (__bf16)u1.z; bv[7] = (__bf16)u1.w;
            *(bf16x8*)&bS[(size_t)(((ks * 4 + ct) * 64 + l) * 8)] = bv;
        }
        colpart_s[cl][h * 4 + q] = ss;
    }
    __syncthreads();

    if (tid < BN) {
        float ssum = 0.f;
#pragma unroll
        for (int p = 0; p < 8; ++p) ssum += colpart_s[tid][p];
        float eps = (src == 0) ? 1e-5f : 1e-12f;
        colinv_s[tid] = 1.0f / fmaxf(sqrtf(ssum), eps);
    }

    // ---- MFMA main loop: wave w -> rows 32w..32w+31 (R = w*2+rt); depth-1 A prefetch.
    floatx4 acc[2][4];
#pragma unroll
    for (int rt = 0; rt < 2; ++rt)
#pragma unroll
        for (int ct = 0; ct < 4; ++ct) acc[rt][ct] = (floatx4){0.f, 0.f, 0.f, 0.f};

    bf16x8 af[2][2];
#pragma unroll
    for (int rt = 0; rt < 2; ++rt)
        af[0][rt] = *(const bf16x8*)(embb_sw + ((size_t)(((w * 2 + rt) * 16 + 0) * 64 + l) << 3));

#pragma unroll
    for (int ks = 0; ks < 16; ++ks) {
        if (ks < 15) {
#pragma unroll
            for (int rt = 0; rt < 2; ++rt)
                af[(ks + 1) & 1][rt] =
                    *(const bf16x8*)(embb_sw + ((size_t)(((w * 2 + rt) * 16 + ks + 1) * 64 + l) << 3));
        }
        bf16x8 bfr[4];
#pragma unroll
        for (int ct = 0; ct < 4; ++ct)
            bfr[ct] = *(const bf16x8*)&bS[(size_t)(((ks * 4 + ct) * 64 + l) * 8)];
#pragma unroll
        for (int rt = 0; rt < 2; ++rt)
#pragma unroll
            for (int ct = 0; ct < 4; ++ct)
                acc[rt][ct] = __builtin_amdgcn_mfma_f32_16x16x32_bf16(af[ks & 1][rt], bfr[ct], acc[rt][ct], 0, 0, 0);
    }

    __syncthreads();   // orders colinv_s writes (pre-loop, tid<64) before epilogue reads

    // ---- epilogue: cos = acc * colinv; label col -> posvals; others -> per-row partial
#pragma unroll
    for (int rt = 0; rt < 2; ++rt) {
#pragma unroll
        for (int r = 0; r < 4; ++r) {
            int row = (w * 2 + rt) * 16 + q * 4 + r;
            int lab = label_s[row];
            float sum = 0.f;
#pragma unroll
            for (int ct = 0; ct < 4; ++ct) {
                int c = c0 + ct * 16 + ln;
                if (c < C) {
                    float cosv = acc[rt][ct][r] * colinv_s[ct * 16 + ln];
                    if (c == lab) posvals[src * B + row] = cosv;  // unique writer per (src,row)
                    else sum += __expf(S_SCALE * cosv);
                }
            }
            sum += __shfl_xor(sum, 1, 64);
            sum += __shfl_xor(sum, 2, 64);
            sum += __shfl_xor(sum, 4, 64);
            sum += __shfl_xor(sum, 8, 64);
            if (ln == 0) partials[(size_t)(src * B + row) * NTILES + tile] = sum;
        }
    }
}

// ---------- reduce partials across tiles: negacc[row] = sum_t partials[row][t] ----------
__global__ void reduce_kernel(const float* __restrict__ partials, float* __restrict__ negacc) {
    int row = blockIdx.x;   // 0 .. 2B-1
    int t = threadIdx.x;    // 256
    float s = 0.f;
    for (int i = t; i < NTILES; i += 256) s += partials[(size_t)row * NTILES + i];
    __shared__ float red[4];
    for (int off = 32; off > 0; off >>= 1) s += __shfl_down(s, off, 64);
    if ((t & 63) == 0) red[t >> 6] = s;
    __syncthreads();
    if (t == 0) negacc[row] = red[0] + red[1] + red[2] + red[3];
}

// ---------- final EPL loss ----------
__global__ void loss_kernel(const float* __restrict__ negacc, const float* __restrict__ posvals,
                            float* __restrict__ out) {
    int t = threadIdx.x;  // 256
    float l1 = log1pf(negacc[t] * __expf(-S_SCALE * (posvals[t] - M_MARGIN)));
    float l2 = log1pf(negacc[B + t] * __expf(-S_SCALE * (1.0f - K_VP) * posvals[B + t]));
    float p = l1 + l2;
    __shared__ float red[4];
    for (int off = 32; off > 0; off >>= 1) p += __shfl_down(p, off, 64);
    if ((t & 63) == 0) red[t >> 6] = p;
    __syncthreads();
    if (t == 0) out[0] = (red[0] + red[1] + red[2] + red[3]) / (2.0f * B);
}

extern "C" void kernel_launch(void* const* d_in, const int* in_sizes, int n_in,
                              void* d_out, int out_size, void* d_ws, size_t ws_size,
                              hipStream_t stream) {
    const float* input  = (const float*)d_in[0];
    const float* weight = (const float*)d_in[1];
    const float* queue  = (const float*)d_in[2];
    const int*   label  = (const int*)d_in[3];
    float* out = (float*)d_out;

    char* ws = (char*)d_ws;
    __bf16* embb_sw  = (__bf16*)(ws);                         // 256 KB
    float*  newrows  = (float*)(ws + (256 << 10));            // 512 KB
    float*  negacc   = (float*)(ws + (768 << 10));            // 2 KB
    float*  posvals  = (float*)(ws + (768 << 10) + 2048);     // 2 KB
    int*    map      = (int*)  (ws + (768 << 10) + 4096);     // 400 KB
    float*  partials = (float*)(ws + (1200 << 10));           // 2B*NTILES*4 = 3.13 MB

    init_kernel<<<(C + 255) / 256, 256, 0, stream>>>(map);
    scatter_kernel<<<1, B, 0, stream>>>(label, map);
    embnew_kernel<<<B, 256, 0, stream>>>(input, queue, label, embb_sw, newrows);
    gemm_epl_kernel<<<2 * NTILES, 512, 0, stream>>>(embb_sw, weight, queue, newrows, map,
                                                    label, partials, posvals);
    reduce_kernel<<<2 * B, 256, 0, stream>>>(partials, negacc);
    loss_kernel<<<1, 256, 0, stream>>>(negacc, posvals, out);
}